// Round 2
// baseline (1359.481 us; speedup 1.0000x reference)
//
#include <hip/hip_runtime.h>

#define NN 8192
#define DIM 128
#define RELS 4

typedef __attribute__((ext_vector_type(8))) short short8;
typedef __attribute__((ext_vector_type(4))) float f32x4;
typedef __attribute__((ext_vector_type(4))) unsigned int u32x4;

__device__ __forceinline__ unsigned short f2bf(float x) {
  union { float f; unsigned u; } v; v.f = x;
  unsigned r = v.u + 0x7FFFu + ((v.u >> 16) & 1u);  // RNE fp32 -> bf16
  return (unsigned short)(r >> 16);
}

// ---------------------------------------------------------------------------
// k1: Yt[r][u][m] = bf16( sum_d X[m][d] * W[r][d][u] )   (transposed output)
// grid 512 = 128 m-tiles x 4 r; block 256 (4 waves), tile 64m x 128u, MFMA.
// ---------------------------------------------------------------------------
__global__ __launch_bounds__(256, 2)
void k1_xw(const float* __restrict__ X, const float* __restrict__ W,
           unsigned short* __restrict__ Yt) {
  __shared__ __align__(16) unsigned short Xs[64 * 136];   // [m][d], pad 8
  __shared__ __align__(16) unsigned short Wt[128 * 136];  // [u][d], pad 8
  const int bid = blockIdx.x;
  const int r = bid & 3;
  const int m0 = (bid >> 2) * 64;
  const int t = threadIdx.x;
  const int w = t >> 6, l = t & 63;

  // stage X tile (64x128 fp32 -> bf16)
  for (int i = 0; i < 8; ++i) {
    int f = t + 256 * i;
    int row = f >> 5, fo = f & 31;
    float4 v = *(const float4*)(X + (size_t)(m0 + row) * DIM + fo * 4);
    ushort4 b = make_ushort4(f2bf(v.x), f2bf(v.y), f2bf(v.z), f2bf(v.w));
    *(ushort4*)&Xs[row * 136 + fo * 4] = b;
  }
  // stage W[r] transposed: Wt[u][d]
  const float* Wr = W + (size_t)r * DIM * DIM;
  for (int i = 0; i < 16; ++i) {
    int f = t + 256 * i;
    int d = f >> 5, uo = (f & 31) * 4;
    float4 v = *(const float4*)(Wr + (size_t)d * DIM + uo);
    Wt[(uo + 0) * 136 + d] = f2bf(v.x);
    Wt[(uo + 1) * 136 + d] = f2bf(v.y);
    Wt[(uo + 2) * 136 + d] = f2bf(v.z);
    Wt[(uo + 3) * 136 + d] = f2bf(v.w);
  }
  __syncthreads();

  const int lm = l & 15, lk = (l >> 4) * 8;
  const int u0 = w * 32;
  f32x4 acc[4][2] = {};
  for (int ks = 0; ks < 4; ++ks) {
    short8 b0 = *(const short8*)&Wt[(u0 + lm) * 136 + ks * 32 + lk];
    short8 b1 = *(const short8*)&Wt[(u0 + 16 + lm) * 136 + ks * 32 + lk];
    for (int mt = 0; mt < 4; ++mt) {
      short8 a = *(const short8*)&Xs[(mt * 16 + lm) * 136 + ks * 32 + lk];
      acc[mt][0] = __builtin_amdgcn_mfma_f32_16x16x32_bf16(a, b0, acc[mt][0], 0, 0, 0);
      acc[mt][1] = __builtin_amdgcn_mfma_f32_16x16x32_bf16(a, b1, acc[mt][1], 0, 0, 0);
    }
  }
  // C/D layout: col(u) = lane&15, row(m) = (lane>>4)*4 + reg  -> 4 consecutive m
  unsigned short* Yb = Yt + (size_t)r * DIM * NN;
  const int mrow = (l >> 4) * 4;
  for (int mt = 0; mt < 4; ++mt)
    for (int ut = 0; ut < 2; ++ut) {
      int u = u0 + ut * 16 + lm;
      int m = m0 + mt * 16 + mrow;
      ushort4 v = make_ushort4(f2bf(acc[mt][ut][0]), f2bf(acc[mt][ut][1]),
                               f2bf(acc[mt][ut][2]), f2bf(acc[mt][ut][3]));
      *(ushort4*)&Yb[(size_t)u * NN + m] = v;
    }
}

// ---------------------------------------------------------------------------
// k2: part[r][n][u] = sum_m adj[r][n][m] * Y[r][m][u]
// grid 512 = 128 n-tiles x 4 r (r = bid&3 -> one r per XCD for L2 locality).
// Block 256: tile 64x128, BK=64, single LDS buffer + register prefetch.
// ---------------------------------------------------------------------------
__global__ __launch_bounds__(256, 2)
void k2_adj(const float* __restrict__ adj, const unsigned short* __restrict__ Yt,
            float* __restrict__ part) {
  __shared__ __align__(16) unsigned short As[64 * 72];    // [m][k], pad 8
  __shared__ __align__(16) unsigned short Bs[128 * 72];   // [u][k], pad 8
  const int bid = blockIdx.x;
  const int r = bid & 3;
  const int m0 = (bid >> 2) * 64;
  const int t = threadIdx.x;
  const int w = t >> 6, l = t & 63;

  const float* Ab = adj + (size_t)r * NN * NN + (size_t)m0 * NN;
  const unsigned short* Bb = Yt + (size_t)r * DIM * NN;

  const int ar = t >> 4, ac = t & 15;   // A: 4 rows/thread, 16B cols
  const int bu = t >> 3, bk = t & 7;    // B: 4 u-rows/thread, 16B segs

  f32x4 ra[4];
  u32x4 rb[4];
  auto issue = [&](int m2) {
    for (int i = 0; i < 4; ++i)
      ra[i] = __builtin_nontemporal_load(
          (const f32x4*)(Ab + (size_t)(ar + 16 * i) * NN + m2 + ac * 4));
    for (int i = 0; i < 4; ++i)
      rb[i] = *(const u32x4*)(Bb + (size_t)(bu + 32 * i) * NN + m2 + bk * 8);
  };

  issue(0);
  const int lm = l & 15, lk = (l >> 4) * 8;
  const int u0 = w * 32;
  f32x4 acc[4][2] = {};

  for (int m2 = 0; m2 < NN; m2 += 64) {
    for (int i = 0; i < 4; ++i) {
      ushort4 b = make_ushort4(f2bf(ra[i].x), f2bf(ra[i].y), f2bf(ra[i].z), f2bf(ra[i].w));
      *(ushort4*)&As[(ar + 16 * i) * 72 + ac * 4] = b;
    }
    for (int i = 0; i < 4; ++i)
      *(u32x4*)&Bs[(bu + 32 * i) * 72 + bk * 8] = rb[i];
    __syncthreads();
    if (m2 + 64 < NN) issue(m2 + 64);   // prefetch next tile during compute
    for (int ks = 0; ks < 2; ++ks) {
      short8 b0 = *(const short8*)&Bs[(u0 + lm) * 72 + ks * 32 + lk];
      short8 b1 = *(const short8*)&Bs[(u0 + 16 + lm) * 72 + ks * 32 + lk];
      for (int mt = 0; mt < 4; ++mt) {
        short8 a = *(const short8*)&As[(mt * 16 + lm) * 72 + ks * 32 + lk];
        acc[mt][0] = __builtin_amdgcn_mfma_f32_16x16x32_bf16(a, b0, acc[mt][0], 0, 0, 0);
        acc[mt][1] = __builtin_amdgcn_mfma_f32_16x16x32_bf16(a, b1, acc[mt][1], 0, 0, 0);
      }
    }
    __syncthreads();
  }

  float* P = part + ((size_t)r * NN + m0) * DIM;
  const int mrow = (l >> 4) * 4;
  for (int mt = 0; mt < 4; ++mt)
    for (int ut = 0; ut < 2; ++ut) {
      int u = u0 + ut * 16 + lm;
      int mb = mt * 16 + mrow;
      for (int i = 0; i < 4; ++i)
        P[(size_t)(mb + i) * DIM + u] = acc[mt][ut][i];
    }
}

// ---------------------------------------------------------------------------
// k3: out = relu(sum_r part[r] + bias)
// ---------------------------------------------------------------------------
__global__ void k3_epi(const float* __restrict__ part, const float* __restrict__ bias,
                       float* __restrict__ out) {
  int g = blockIdx.x * 256 + threadIdx.x;       // float4 index, 262144 total
  const float4* p = (const float4*)part;
  float4 s0 = p[g];
  float4 s1 = p[g + 262144];
  float4 s2 = p[g + 2 * 262144];
  float4 s3 = p[g + 3 * 262144];
  float4 b = ((const float4*)bias)[g & 31];
  float4 o;
  o.x = fmaxf(s0.x + s1.x + s2.x + s3.x + b.x, 0.f);
  o.y = fmaxf(s0.y + s1.y + s2.y + s3.y + b.y, 0.f);
  o.z = fmaxf(s0.z + s1.z + s2.z + s3.z + b.z, 0.f);
  o.w = fmaxf(s0.w + s1.w + s2.w + s3.w + b.w, 0.f);
  ((float4*)out)[g] = o;
}

extern "C" void kernel_launch(void* const* d_in, const int* in_sizes, int n_in,
                              void* d_out, int out_size, void* d_ws, size_t ws_size,
                              hipStream_t stream) {
  const float* X    = (const float*)d_in[0];   // [8192][128]
  const float* adj  = (const float*)d_in[1];   // [4][8192][8192]
  const float* W    = (const float*)d_in[2];   // [4][128][128]
  const float* bias = (const float*)d_in[3];   // [128]
  float* out = (float*)d_out;                  // [8192][128]

  // ws: Yt bf16 [4][128][8192] (8 MB) | part fp32 [4][8192][128] (16 MB)
  unsigned short* Yt = (unsigned short*)d_ws;
  float* part = (float*)((char*)d_ws + (size_t)RELS * DIM * NN * sizeof(unsigned short));

  k1_xw<<<dim3(512), dim3(256), 0, stream>>>(X, W, Yt);
  k2_adj<<<dim3(512), dim3(256), 0, stream>>>(adj, Yt, part);
  k3_epi<<<dim3(1024), dim3(256), 0, stream>>>(part, bias, out);
}